// Round 14
// baseline (68.226 us; speedup 1.0000x reference)
//
#include <hip/hip_runtime.h>
#include <hip/hip_fp16.h>

#define N_NODES 50000
#define N_EDGES 800000
#define D 96
#define D4 (D / 4)           // 24 float4 chunks per f32 row

#define BIN_SH 6             // bin = row >> 6 (64 nodes per bin)
#define BIN_NODES 64
#define NBINS 782            // ceil(50000 / 64)
#define MAXB 1536            // fixed bin capacity (mean 1024, sigma 32 -> +16 sigma)
#define NB2 256              // K2 sort buckets: localrow*4 + col-quartile

#define TBLOCKS 782          // transform blocks: 782*4 waves >= 3125 M-tiles
#define SBLOCKS 392          // scatter blocks
#define EPB 2041             // ceil(N_EDGES / SBLOCKS)
#define WT_LD 104            // fp16 W^T leading dim (208 B, 16B-aligned)
#define OUT_LD 104           // per-wave repack tile leading dim (halves)
#define SMEM_INTS 5000       // 20,000 B union (8 blocks/CU preserved)

typedef _Float16 f16x8 __attribute__((ext_vector_type(8)));
typedef float    f32x4 __attribute__((ext_vector_type(4)));

// ===========================================================================
// K1 (r13-proven): bid < TBLOCKS : y(fp16) = x @ W via mfma_f32_16x16x32_f16,
//   C-fragments in regs, WT LDS region reused post-barrier for repack ->
//   3 coalesced dwordx4 stores/lane. bid >= TBLOCKS: reg-cached binscatter.
// ===========================================================================
__global__ __launch_bounds__(256) void transform_scatter(
        const float* __restrict__ x, const float* __restrict__ W,
        const int* __restrict__ row, const int* __restrict__ col,
        const float* __restrict__ edge_w,
        __half* __restrict__ y, int* __restrict__ cursor,
        int2* __restrict__ binned) {
    __shared__ __align__(16) int smem[SMEM_INTS];
    const int t = threadIdx.x;
    const int bid = blockIdx.x;

    if (bid >= TBLOCKS) {
        // ---------------- binscatter (reg-cached edges) ----------------
        int* lh    = smem;
        int* gbase = smem + NBINS;
        int* lcur  = smem + 2 * NBINS;
        for (int i = t; i < NBINS; i += 256) { lh[i] = 0; lcur[i] = 0; }
        __syncthreads();
        int e0 = (bid - TBLOCKS) * EPB;
        int e1 = min(e0 + EPB, N_EDGES);
        int   ex[8];   // col | lr<<16 | bin<<22  (-1 = invalid)
        float ew[8];
        #pragma unroll
        for (int i = 0; i < 8; ++i) {
            int e = e0 + t + i * 256;
            bool v = e < e1;
            int r  = v ? row[e] : 0;
            int cc = v ? col[e] : 0;
            ew[i]  = v ? edge_w[e] : 0.0f;
            int b  = r >> BIN_SH;
            ex[i]  = v ? (cc | ((r & 63) << 16) | (b << 22)) : -1;
            if (v) atomicAdd(&lh[b], 1);
        }
        __syncthreads();
        for (int i = t; i < NBINS; i += 256)
            gbase[i] = lh[i] ? (i * MAXB + atomicAdd(&cursor[i], lh[i])) : 0;
        __syncthreads();
        #pragma unroll
        for (int i = 0; i < 8; ++i) {
            if (ex[i] != -1) {
                int b = (unsigned)ex[i] >> 22;
                int p = atomicAdd(&lcur[b], 1);
                binned[gbase[b] + p] = make_int2(ex[i] & 0x3FFFFF,
                                                 __float_as_int(ew[i]));
            }
        }
        return;
    }

    // ---------------- MFMA transform ----------------
    _Float16* WT = reinterpret_cast<_Float16*>(smem);
    for (int i = t; i < D * D; i += 256) {
        int k = i / D, n2 = i % D;            // read W coalesced (k-major)
        WT[n2 * WT_LD + k] = (_Float16)W[i];
    }
    __syncthreads();

    const int lane = t & 63;
    const int wv   = t >> 6;
    const int wid  = bid * 4 + wv;            // M-tile id, 0..3127
    const int n0   = wid * 16;
    const bool active = (n0 < N_NODES);       // 50000 = 3125*16 exactly

    const int arow = lane & 15;
    const int kgrp = lane >> 4;               // 0..3 (K-group of 8)
    const int bcol = lane & 15;

    f32x4 acc6[6];
    #pragma unroll
    for (int nt = 0; nt < 6; ++nt) acc6[nt] = (f32x4){0.f, 0.f, 0.f, 0.f};

    if (active) {
        const float4* xr = reinterpret_cast<const float4*>(x) +
                           (long long)(n0 + arow) * D4;
        f16x8 afrag[3];
        #pragma unroll
        for (int ks = 0; ks < 3; ++ks) {
            float4 v0 = xr[ks * 8 + kgrp * 2];
            float4 v1 = xr[ks * 8 + kgrp * 2 + 1];
            f16x8 a;
            a[0] = (_Float16)v0.x; a[1] = (_Float16)v0.y;
            a[2] = (_Float16)v0.z; a[3] = (_Float16)v0.w;
            a[4] = (_Float16)v1.x; a[5] = (_Float16)v1.y;
            a[6] = (_Float16)v1.z; a[7] = (_Float16)v1.w;
            afrag[ks] = a;
        }
        #pragma unroll
        for (int nt = 0; nt < 6; ++nt) {
            #pragma unroll
            for (int ks = 0; ks < 3; ++ks) {
                f16x8 b = *reinterpret_cast<const f16x8*>(
                    &WT[(nt * 16 + bcol) * WT_LD + ks * 32 + kgrp * 8]);
                acc6[nt] = __builtin_amdgcn_mfma_f32_16x16x32_f16(afrag[ks], b,
                                                                  acc6[nt], 0, 0, 0);
            }
        }
    }
    __syncthreads();           // all waves done reading WT -> safe to reuse

    if (active) {
        _Float16* outl = WT + wv * (16 * OUT_LD);
        // C layout: col = lane&15, row = (lane>>4)*4 + i  (m89-verified)
        #pragma unroll
        for (int nt = 0; nt < 6; ++nt)
            #pragma unroll
            for (int i = 0; i < 4; ++i)
                outl[(kgrp * 4 + i) * OUT_LD + nt * 16 + bcol] =
                    (_Float16)acc6[nt][i];
        // in-wave LDS dependency only -> no extra barrier needed
        #pragma unroll
        for (int r = 0; r < 3; ++r) {
            int cch = lane + r * 64;
            int rw = cch / 12, sb = cch % 12;
            uint4 v = *reinterpret_cast<const uint4*>(outl + rw * OUT_LD + sb * 8);
            *reinterpret_cast<uint4*>(y + (long long)(n0 + rw) * D + sb * 8) = v;
        }
    }
}

// ===========================================================================
// K2: binsort_aggregate - one 768-thread block per 64-node bin.
// Counting sort by (localrow*4 + col-quartile) -> L2-phased gather.
// Scan: single-wave shuffle scan (no block barriers). Gather: unroll x4.
// ===========================================================================
__global__ __launch_bounds__(768) void binsort_aggregate(
        const int* __restrict__ cursor, const int2* __restrict__ binned,
        const __half* __restrict__ y, const float* __restrict__ bias,
        float* __restrict__ out) {
    __shared__ int2 recs[MAXB];          // 12 KB
    __shared__ int hist[NB2];
    __shared__ int lcur[NB2];
    __shared__ int nodeoff[NB2 + 1];
    int t = threadIdx.x;
    int b = blockIdx.x;
    int base = b * MAXB;
    int size = cursor[b];
    if (size > MAXB) size = MAXB;        // statistically impossible; mem safety
    if (t < NB2) hist[t] = 0;
    __syncthreads();

    // key = localrow*4 + col/12500  (col <= 49999 -> quartile 0..3)
    int2 rl0, rl1;
    int k0 = -1, k1 = -1;
    int i0 = t, i1 = t + 768;
    if (i0 < size) {
        rl0 = binned[base + i0];
        k0 = (((rl0.x >> 16) & 63) << 2) + (rl0.x & 0xFFFF) / 12500;
        atomicAdd(&hist[k0], 1);
    }
    if (i1 < size) {
        rl1 = binned[base + i1];
        k1 = (((rl1.x >> 16) & 63) << 2) + (rl1.x & 0xFFFF) / 12500;
        atomicAdd(&hist[k1], 1);
    }
    __syncthreads();

    // single-wave exclusive scan of 256 buckets (wave 0, 4 values/lane)
    if (t < 64) {
        int v0 = hist[t];
        int v1 = hist[t + 64];
        int v2 = hist[t + 128];
        int v3 = hist[t + 192];
        int s0 = v0, s1 = v1, s2 = v2, s3 = v3;
        #pragma unroll
        for (int off = 1; off < 64; off <<= 1) {
            int u0 = __shfl_up(s0, off);
            int u1 = __shfl_up(s1, off);
            int u2 = __shfl_up(s2, off);
            int u3 = __shfl_up(s3, off);
            if (t >= off) { s0 += u0; s1 += u1; s2 += u2; s3 += u3; }
        }
        int t0 = __shfl(s0, 63);
        s1 += t0;
        int t1 = __shfl(s1, 63);
        s2 += t1;
        int t2 = __shfl(s2, 63);
        s3 += t2;
        nodeoff[t]       = s0 - v0;  lcur[t]       = s0 - v0;
        nodeoff[t + 64]  = s1 - v1;  lcur[t + 64]  = s1 - v1;
        nodeoff[t + 128] = s2 - v2;  lcur[t + 128] = s2 - v2;
        nodeoff[t + 192] = s3 - v3;  lcur[t + 192] = s3 - v3;
        if (t == 63) nodeoff[NB2] = s3;   // == size
    }
    __syncthreads();

    if (k0 >= 0) { int p = atomicAdd(&lcur[k0], 1);
                   recs[p] = make_int2(rl0.x & 0xFFFF, rl0.y); }
    if (k1 >= 0) { int p = atomicAdd(&lcur[k1], 1);
                   recs[p] = make_int2(rl1.x & 0xFFFF, rl1.y); }
    __syncthreads();

    const uint4* yu = reinterpret_cast<const uint4*>(y);
    int c = t % 12;
    int g = t / 12;                      // 0..63
    int n = (b << BIN_SH) + g;
    if (n >= N_NODES) return;
    int beg = nodeoff[g << 2];
    int end = nodeoff[(g + 1) << 2];

    float A0[8], A1[8], A2[8], A3[8];
    #pragma unroll
    for (int i = 0; i < 8; ++i) { A0[i] = 0.f; A1[i] = 0.f; A2[i] = 0.f; A3[i] = 0.f; }

    auto gstep = [&](int2 rec, float (&A)[8]) {
        float w = __int_as_float(rec.y);
        uint4 v = yu[(long long)rec.x * 12 + c];
        float2 f0 = __half22float2(*reinterpret_cast<const __half2*>(&v.x));
        float2 f1 = __half22float2(*reinterpret_cast<const __half2*>(&v.y));
        float2 f2 = __half22float2(*reinterpret_cast<const __half2*>(&v.z));
        float2 f3 = __half22float2(*reinterpret_cast<const __half2*>(&v.w));
        A[0] = fmaf(w, f0.x, A[0]);
        A[1] = fmaf(w, f0.y, A[1]);
        A[2] = fmaf(w, f1.x, A[2]);
        A[3] = fmaf(w, f1.y, A[3]);
        A[4] = fmaf(w, f2.x, A[4]);
        A[5] = fmaf(w, f2.y, A[5]);
        A[6] = fmaf(w, f3.x, A[6]);
        A[7] = fmaf(w, f3.y, A[7]);
    };

    int j = beg;
    for (; j + 3 < end; j += 4) {
        gstep(recs[j],     A0);
        gstep(recs[j + 1], A1);
        gstep(recs[j + 2], A2);
        gstep(recs[j + 3], A3);
    }
    for (; j < end; ++j) gstep(recs[j], A0);

    #pragma unroll
    for (int i = 0; i < 8; ++i) A0[i] += A1[i] + A2[i] + A3[i];

    const float4* b4 = reinterpret_cast<const float4*>(bias);
    float4 ba = b4[c * 2], bb = b4[c * 2 + 1];
    float4 o0, o1;
    o0.x = fmaxf(A0[0] + ba.x, 0.f);
    o0.y = fmaxf(A0[1] + ba.y, 0.f);
    o0.z = fmaxf(A0[2] + ba.z, 0.f);
    o0.w = fmaxf(A0[3] + ba.w, 0.f);
    o1.x = fmaxf(A0[4] + bb.x, 0.f);
    o1.y = fmaxf(A0[5] + bb.y, 0.f);
    o1.z = fmaxf(A0[6] + bb.z, 0.f);
    o1.w = fmaxf(A0[7] + bb.w, 0.f);
    float4* op = reinterpret_cast<float4*>(&out[(long long)n * D + c * 8]);
    op[0] = o0;
    op[1] = o1;
}

// ===========================================================================
// Minimal fallback (ws too small): round-1 proven 3-kernel path
// ===========================================================================
__global__ void zero_f32(float* __restrict__ p, long long n) {
    long long i = (long long)blockIdx.x * blockDim.x + threadIdx.x;
    long long stride = (long long)gridDim.x * blockDim.x;
    for (; i < n; i += stride) p[i] = 0.0f;
}

__global__ __launch_bounds__(256) void scatter_edges(
        const float* __restrict__ x, const float* __restrict__ edge_w,
        const int* __restrict__ row, const int* __restrict__ col,
        float* __restrict__ hidden) {
    long long t = (long long)blockIdx.x * blockDim.x + threadIdx.x;
    const long long total = (long long)N_EDGES * D4;
    if (t >= total) return;
    int e = (int)(t / D4);
    int c = (int)(t % D4);
    float w = edge_w[e];
    const float4 v = *reinterpret_cast<const float4*>(&x[(long long)col[e] * D + c * 4]);
    float* o = &hidden[(long long)row[e] * D + c * 4];
    atomicAdd(o + 0, w * v.x);
    atomicAdd(o + 1, w * v.y);
    atomicAdd(o + 2, w * v.z);
    atomicAdd(o + 3, w * v.w);
}

__global__ __launch_bounds__(256) void gemm_bias_relu(
        const float* __restrict__ hidden, const float* __restrict__ W,
        const float* __restrict__ bias, float* __restrict__ out) {
    __shared__ float Ws[D * D];
    __shared__ float bs[D];
    for (int i = threadIdx.x; i < D * D; i += blockDim.x) Ws[i] = W[i];
    if (threadIdx.x < D) bs[threadIdx.x] = bias[threadIdx.x];
    __syncthreads();
    const long long total = (long long)N_NODES * D;
    long long stride = (long long)gridDim.x * blockDim.x;
    for (long long idx = (long long)blockIdx.x * blockDim.x + threadIdx.x;
         idx < total; idx += stride) {
        int n = (int)(idx / D);
        int d = (int)(idx % D);
        const float* hrow = &hidden[(long long)n * D];
        float acc = bs[d];
        #pragma unroll
        for (int k = 0; k < D; ++k) acc = fmaf(hrow[k], Ws[k * D + d], acc);
        out[idx] = fmaxf(acc, 0.0f);
    }
}

// ===========================================================================
extern "C" void kernel_launch(void* const* d_in, const int* in_sizes, int n_in,
                              void* d_out, int out_size, void* d_ws, size_t ws_size,
                              hipStream_t stream) {
    const float* x      = (const float*)d_in[0];
    const float* edge_w = (const float*)d_in[1];
    const float* weight = (const float*)d_in[2];
    const float* bias   = (const float*)d_in[3];
    const int*   row    = (const int*)d_in[4];
    const int*   col    = (const int*)d_in[5];
    float* out = (float*)d_out;

    const size_t yBytes      = (size_t)N_NODES * D * sizeof(__half);     // 9,600,000
    const size_t binnedBytes = (size_t)NBINS * MAXB * sizeof(int2);      // 9,609,216
    const size_t curBytes    = (size_t)NBINS * sizeof(int);
    const size_t need = yBytes + binnedBytes + curBytes + 64;

    if (ws_size >= need) {
        char* wsb = (char*)d_ws;
        __half* y      = (__half*)wsb; wsb += yBytes;
        int2*   binned = (int2*)wsb;   wsb += binnedBytes;
        int*    cursor = (int*)wsb;

        hipMemsetAsync(cursor, 0, curBytes, stream);
        transform_scatter<<<TBLOCKS + SBLOCKS, 256, 0, stream>>>(
            x, weight, row, col, edge_w, y, cursor, binned);
        binsort_aggregate<<<NBINS, 768, 0, stream>>>(cursor, binned, y, bias, out);
    } else {
        float* hidden = (float*)d_ws;
        const long long hidden_elems = (long long)N_NODES * D;
        zero_f32<<<2048, 256, 0, stream>>>(hidden, hidden_elems);
        long long total = (long long)N_EDGES * D4;
        scatter_edges<<<(int)((total + 255) / 256), 256, 0, stream>>>(x, edge_w, row,
                                                                      col, hidden);
        gemm_bias_relu<<<2048, 256, 0, stream>>>(hidden, weight, bias, out);
    }
}

// Round 15
// 62.354 us; speedup vs baseline: 1.0942x; 1.0942x over previous
//
#include <hip/hip_runtime.h>
#include <hip/hip_fp16.h>

#define N_NODES 50000
#define N_EDGES 800000
#define D 96
#define D4 (D / 4)           // 24 float4 chunks per f32 row

#define BIN_SH 6             // bin = row >> 6 (64 nodes per bin)
#define BIN_NODES 64
#define NBINS 782            // ceil(50000 / 64)
#define MAXB 1536            // fixed bin capacity (mean 1024, sigma 32 -> +16 sigma)
#define NB2 256              // K2 sort buckets: localrow*4 + col-quartile

#define TBLOCKS 782          // transform blocks: 782*4 waves >= 3125 M-tiles
#define SBLOCKS 392          // scatter blocks
#define EPB 2041             // ceil(N_EDGES / SBLOCKS)
#define WT_LD 104            // fp16 W^T leading dim (208 B, 16B-aligned)

typedef _Float16 f16x8 __attribute__((ext_vector_type(8)));
typedef float    f32x4 __attribute__((ext_vector_type(4)));

// ===========================================================================
// K1: bid < TBLOCKS : y(fp16) = x @ W via mfma_f32_16x16x32_f16
//     bid >= TBLOCKS: binscatter, edges cached in regs (single global read)
// (exact r11 version - best measured: 61.3 us total)
// ===========================================================================
__global__ __launch_bounds__(256) void transform_scatter(
        const float* __restrict__ x, const float* __restrict__ W,
        const int* __restrict__ row, const int* __restrict__ col,
        const float* __restrict__ edge_w,
        __half* __restrict__ y, int* __restrict__ cursor,
        int2* __restrict__ binned) {
    __shared__ __align__(16) int smem[5000];   // 20,000 B union
    const int t = threadIdx.x;
    const int bid = blockIdx.x;

    if (bid >= TBLOCKS) {
        // ---------------- binscatter (reg-cached edges) ----------------
        int* lh    = smem;
        int* gbase = smem + NBINS;
        int* lcur  = smem + 2 * NBINS;
        for (int i = t; i < NBINS; i += 256) { lh[i] = 0; lcur[i] = 0; }
        __syncthreads();
        int e0 = (bid - TBLOCKS) * EPB;
        int e1 = min(e0 + EPB, N_EDGES);
        int   ex[8];   // col | lr<<16 | bin<<22  (-1 = invalid; bin<=781<1023)
        float ew[8];
        #pragma unroll
        for (int i = 0; i < 8; ++i) {
            int e = e0 + t + i * 256;
            bool v = e < e1;
            int r  = v ? row[e] : 0;
            int cc = v ? col[e] : 0;
            ew[i]  = v ? edge_w[e] : 0.0f;
            int b  = r >> BIN_SH;
            ex[i]  = v ? (cc | ((r & 63) << 16) | (b << 22)) : -1;
            if (v) atomicAdd(&lh[b], 1);
        }
        __syncthreads();
        for (int i = t; i < NBINS; i += 256)
            gbase[i] = lh[i] ? (i * MAXB + atomicAdd(&cursor[i], lh[i])) : 0;
        __syncthreads();
        #pragma unroll
        for (int i = 0; i < 8; ++i) {
            if (ex[i] != -1) {
                int b = (unsigned)ex[i] >> 22;
                int p = atomicAdd(&lcur[b], 1);
                binned[gbase[b] + p] = make_int2(ex[i] & 0x3FFFFF,
                                                 __float_as_int(ew[i]));
            }
        }
        return;
    }

    // ---------------- MFMA transform ----------------
    _Float16* WT = reinterpret_cast<_Float16*>(smem);
    for (int i = t; i < D * D; i += 256) {
        int k = i / D, n2 = i % D;            // read W coalesced (k-major)
        WT[n2 * WT_LD + k] = (_Float16)W[i];
    }
    __syncthreads();

    const int lane = t & 63;
    const int wv   = t >> 6;
    const int wid  = bid * 4 + wv;            // M-tile id, 0..3127
    const int n0   = wid * 16;
    if (n0 >= N_NODES) return;

    const int arow = lane & 15;
    const int kgrp = lane >> 4;               // 0..3 (K-group of 8)

    const float4* xr = reinterpret_cast<const float4*>(x) +
                       (long long)(n0 + arow) * D4;
    f16x8 afrag[3];
    #pragma unroll
    for (int ks = 0; ks < 3; ++ks) {
        float4 v0 = xr[ks * 8 + kgrp * 2];
        float4 v1 = xr[ks * 8 + kgrp * 2 + 1];
        f16x8 a;
        a[0] = (_Float16)v0.x; a[1] = (_Float16)v0.y;
        a[2] = (_Float16)v0.z; a[3] = (_Float16)v0.w;
        a[4] = (_Float16)v1.x; a[5] = (_Float16)v1.y;
        a[6] = (_Float16)v1.z; a[7] = (_Float16)v1.w;
        afrag[ks] = a;
    }

    const int bcol = lane & 15;
    #pragma unroll
    for (int nt = 0; nt < 6; ++nt) {
        f32x4 acc = {0.f, 0.f, 0.f, 0.f};
        #pragma unroll
        for (int ks = 0; ks < 3; ++ks) {
            f16x8 b = *reinterpret_cast<const f16x8*>(
                &WT[(nt * 16 + bcol) * WT_LD + ks * 32 + kgrp * 8]);
            acc = __builtin_amdgcn_mfma_f32_16x16x32_f16(afrag[ks], b, acc, 0, 0, 0);
        }
        // C layout: col = lane&15, row = (lane>>4)*4 + i  (m89-verified)
        #pragma unroll
        for (int i = 0; i < 4; ++i) {
            int rrow = kgrp * 4 + i;
            y[(long long)(n0 + rrow) * D + nt * 16 + bcol] = __float2half_rn(acc[i]);
        }
    }
}

// ===========================================================================
// K2: binsort_aggregate - one 768-thread block per 64-node bin.
// Counting sort by (localrow*4 + col-quartile): per-node records come in
// ascending col-quartile -> co-resident blocks sweep y in rough phase
// (L2-resident working set). Gather loop unrolled x2.
// (exact r11 version - best measured)
// ===========================================================================
__global__ __launch_bounds__(768) void binsort_aggregate(
        const int* __restrict__ cursor, const int2* __restrict__ binned,
        const __half* __restrict__ y, const float* __restrict__ bias,
        float* __restrict__ out) {
    __shared__ int2 recs[MAXB];          // 12 KB
    __shared__ int hist[NB2];
    __shared__ int sc[NB2];
    __shared__ int lcur[NB2];
    __shared__ int nodeoff[NB2 + 1];
    int t = threadIdx.x;
    int b = blockIdx.x;
    int base = b * MAXB;
    int size = cursor[b];
    if (size > MAXB) size = MAXB;        // statistically impossible; mem safety
    if (t < NB2) hist[t] = 0;
    __syncthreads();

    // key = localrow*4 + col/12500  (col <= 49999 -> quartile 0..3)
    int2 rl0, rl1;
    int k0 = -1, k1 = -1;
    int i0 = t, i1 = t + 768;
    if (i0 < size) {
        rl0 = binned[base + i0];
        k0 = (((rl0.x >> 16) & 63) << 2) + (rl0.x & 0xFFFF) / 12500;
        atomicAdd(&hist[k0], 1);
    }
    if (i1 < size) {
        rl1 = binned[base + i1];
        k1 = (((rl1.x >> 16) & 63) << 2) + (rl1.x & 0xFFFF) / 12500;
        atomicAdd(&hist[k1], 1);
    }
    __syncthreads();

    int h = 0;
    if (t < NB2) { h = hist[t]; sc[t] = h; }
    for (int off = 1; off < NB2; off <<= 1) {
        __syncthreads();
        int a = (t >= off && t < NB2) ? sc[t - off] : 0;
        __syncthreads();
        if (t < NB2) sc[t] += a;
    }
    __syncthreads();
    if (t < NB2) { int excl = sc[t] - h; nodeoff[t] = excl; lcur[t] = excl; }
    if (t == 0) nodeoff[NB2] = size;
    __syncthreads();

    if (k0 >= 0) { int p = atomicAdd(&lcur[k0], 1);
                   recs[p] = make_int2(rl0.x & 0xFFFF, rl0.y); }
    if (k1 >= 0) { int p = atomicAdd(&lcur[k1], 1);
                   recs[p] = make_int2(rl1.x & 0xFFFF, rl1.y); }
    __syncthreads();

    const uint4* yu = reinterpret_cast<const uint4*>(y);
    int c = t % 12;
    int g = t / 12;                      // 0..63
    int n = (b << BIN_SH) + g;
    if (n >= N_NODES) return;
    int beg = nodeoff[g << 2];
    int end = nodeoff[(g + 1) << 2];

    float acc[8], acc2[8];
    #pragma unroll
    for (int i = 0; i < 8; ++i) { acc[i] = 0.0f; acc2[i] = 0.0f; }

    int j = beg;
    for (; j + 1 < end; j += 2) {
        int2 r0 = recs[j];
        int2 r1 = recs[j + 1];
        float w0 = __int_as_float(r0.y);
        float w1 = __int_as_float(r1.y);
        uint4 v0 = yu[(long long)r0.x * 12 + c];
        uint4 v1 = yu[(long long)r1.x * 12 + c];
        float2 a0 = __half22float2(*reinterpret_cast<const __half2*>(&v0.x));
        float2 a1 = __half22float2(*reinterpret_cast<const __half2*>(&v0.y));
        float2 a2 = __half22float2(*reinterpret_cast<const __half2*>(&v0.z));
        float2 a3 = __half22float2(*reinterpret_cast<const __half2*>(&v0.w));
        acc[0] = fmaf(w0, a0.x, acc[0]);
        acc[1] = fmaf(w0, a0.y, acc[1]);
        acc[2] = fmaf(w0, a1.x, acc[2]);
        acc[3] = fmaf(w0, a1.y, acc[3]);
        acc[4] = fmaf(w0, a2.x, acc[4]);
        acc[5] = fmaf(w0, a2.y, acc[5]);
        acc[6] = fmaf(w0, a3.x, acc[6]);
        acc[7] = fmaf(w0, a3.y, acc[7]);
        float2 b0 = __half22float2(*reinterpret_cast<const __half2*>(&v1.x));
        float2 b1 = __half22float2(*reinterpret_cast<const __half2*>(&v1.y));
        float2 b2 = __half22float2(*reinterpret_cast<const __half2*>(&v1.z));
        float2 b3 = __half22float2(*reinterpret_cast<const __half2*>(&v1.w));
        acc2[0] = fmaf(w1, b0.x, acc2[0]);
        acc2[1] = fmaf(w1, b0.y, acc2[1]);
        acc2[2] = fmaf(w1, b1.x, acc2[2]);
        acc2[3] = fmaf(w1, b1.y, acc2[3]);
        acc2[4] = fmaf(w1, b2.x, acc2[4]);
        acc2[5] = fmaf(w1, b2.y, acc2[5]);
        acc2[6] = fmaf(w1, b3.x, acc2[6]);
        acc2[7] = fmaf(w1, b3.y, acc2[7]);
    }
    if (j < end) {
        int2 r0 = recs[j];
        float w0 = __int_as_float(r0.y);
        uint4 v0 = yu[(long long)r0.x * 12 + c];
        float2 a0 = __half22float2(*reinterpret_cast<const __half2*>(&v0.x));
        float2 a1 = __half22float2(*reinterpret_cast<const __half2*>(&v0.y));
        float2 a2 = __half22float2(*reinterpret_cast<const __half2*>(&v0.z));
        float2 a3 = __half22float2(*reinterpret_cast<const __half2*>(&v0.w));
        acc[0] = fmaf(w0, a0.x, acc[0]);
        acc[1] = fmaf(w0, a0.y, acc[1]);
        acc[2] = fmaf(w0, a1.x, acc[2]);
        acc[3] = fmaf(w0, a1.y, acc[3]);
        acc[4] = fmaf(w0, a2.x, acc[4]);
        acc[5] = fmaf(w0, a2.y, acc[5]);
        acc[6] = fmaf(w0, a3.x, acc[6]);
        acc[7] = fmaf(w0, a3.y, acc[7]);
    }
    #pragma unroll
    for (int i = 0; i < 8; ++i) acc[i] += acc2[i];

    const float4* b4 = reinterpret_cast<const float4*>(bias);
    float4 ba = b4[c * 2], bb = b4[c * 2 + 1];
    float4 o0, o1;
    o0.x = fmaxf(acc[0] + ba.x, 0.f);
    o0.y = fmaxf(acc[1] + ba.y, 0.f);
    o0.z = fmaxf(acc[2] + ba.z, 0.f);
    o0.w = fmaxf(acc[3] + ba.w, 0.f);
    o1.x = fmaxf(acc[4] + bb.x, 0.f);
    o1.y = fmaxf(acc[5] + bb.y, 0.f);
    o1.z = fmaxf(acc[6] + bb.z, 0.f);
    o1.w = fmaxf(acc[7] + bb.w, 0.f);
    float4* op = reinterpret_cast<float4*>(&out[(long long)n * D + c * 8]);
    op[0] = o0;
    op[1] = o1;
}

// ===========================================================================
// Minimal fallback (ws too small): round-1 proven 3-kernel path
// ===========================================================================
__global__ void zero_f32(float* __restrict__ p, long long n) {
    long long i = (long long)blockIdx.x * blockDim.x + threadIdx.x;
    long long stride = (long long)gridDim.x * blockDim.x;
    for (; i < n; i += stride) p[i] = 0.0f;
}

__global__ __launch_bounds__(256) void scatter_edges(
        const float* __restrict__ x, const float* __restrict__ edge_w,
        const int* __restrict__ row, const int* __restrict__ col,
        float* __restrict__ hidden) {
    long long t = (long long)blockIdx.x * blockDim.x + threadIdx.x;
    const long long total = (long long)N_EDGES * D4;
    if (t >= total) return;
    int e = (int)(t / D4);
    int c = (int)(t % D4);
    float w = edge_w[e];
    const float4 v = *reinterpret_cast<const float4*>(&x[(long long)col[e] * D + c * 4]);
    float* o = &hidden[(long long)row[e] * D + c * 4];
    atomicAdd(o + 0, w * v.x);
    atomicAdd(o + 1, w * v.y);
    atomicAdd(o + 2, w * v.z);
    atomicAdd(o + 3, w * v.w);
}

__global__ __launch_bounds__(256) void gemm_bias_relu(
        const float* __restrict__ hidden, const float* __restrict__ W,
        const float* __restrict__ bias, float* __restrict__ out) {
    __shared__ float Ws[D * D];
    __shared__ float bs[D];
    for (int i = threadIdx.x; i < D * D; i += blockDim.x) Ws[i] = W[i];
    if (threadIdx.x < D) bs[threadIdx.x] = bias[threadIdx.x];
    __syncthreads();
    const long long total = (long long)N_NODES * D;
    long long stride = (long long)gridDim.x * blockDim.x;
    for (long long idx = (long long)blockIdx.x * blockDim.x + threadIdx.x;
         idx < total; idx += stride) {
        int n = (int)(idx / D);
        int d = (int)(idx % D);
        const float* hrow = &hidden[(long long)n * D];
        float acc = bs[d];
        #pragma unroll
        for (int k = 0; k < D; ++k) acc = fmaf(hrow[k], Ws[k * D + d], acc);
        out[idx] = fmaxf(acc, 0.0f);
    }
}

// ===========================================================================
extern "C" void kernel_launch(void* const* d_in, const int* in_sizes, int n_in,
                              void* d_out, int out_size, void* d_ws, size_t ws_size,
                              hipStream_t stream) {
    const float* x      = (const float*)d_in[0];
    const float* edge_w = (const float*)d_in[1];
    const float* weight = (const float*)d_in[2];
    const float* bias   = (const float*)d_in[3];
    const int*   row    = (const int*)d_in[4];
    const int*   col    = (const int*)d_in[5];
    float* out = (float*)d_out;

    const size_t yBytes      = (size_t)N_NODES * D * sizeof(__half);     // 9,600,000
    const size_t binnedBytes = (size_t)NBINS * MAXB * sizeof(int2);      // 9,609,216
    const size_t curBytes    = (size_t)NBINS * sizeof(int);
    const size_t need = yBytes + binnedBytes + curBytes + 64;

    if (ws_size >= need) {
        char* wsb = (char*)d_ws;
        __half* y      = (__half*)wsb; wsb += yBytes;
        int2*   binned = (int2*)wsb;   wsb += binnedBytes;
        int*    cursor = (int*)wsb;

        hipMemsetAsync(cursor, 0, curBytes, stream);
        transform_scatter<<<TBLOCKS + SBLOCKS, 256, 0, stream>>>(
            x, weight, row, col, edge_w, y, cursor, binned);
        binsort_aggregate<<<NBINS, 768, 0, stream>>>(cursor, binned, y, bias, out);
    } else {
        float* hidden = (float*)d_ws;
        const long long hidden_elems = (long long)N_NODES * D;
        zero_f32<<<2048, 256, 0, stream>>>(hidden, hidden_elems);
        long long total = (long long)N_EDGES * D4;
        scatter_edges<<<(int)((total + 255) / 256), 256, 0, stream>>>(x, edge_w, row,
                                                                      col, hidden);
        gemm_bias_relu<<<2048, 256, 0, stream>>>(hidden, weight, bias, out);
    }
}